// Round 7
// baseline (227.038 us; speedup 1.0000x reference)
//
#include <hip/hip_runtime.h>

typedef unsigned short u16;
typedef unsigned int u32;
typedef __bf16 bf16x8 __attribute__((ext_vector_type(8)));
typedef float f32x4 __attribute__((ext_vector_type(4)));
typedef u32 u32x2 __attribute__((ext_vector_type(2)));
typedef u32 u32x4 __attribute__((ext_vector_type(4)));

#define M_DIM 8192

__device__ __forceinline__ u16 f2bf(float f) {
  return __builtin_bit_cast(u16, (__bf16)f);  // HW RNE cvt
}

union Frag {
  bf16x8 f;
  u16 s[8];
  u32x2 h2[2];
  u32x4 q;
};

// zbt layout: ((kt*2 + nt)*64 + lane)*8 + j holds z[k = kt*32 + 8*(lane>>4)+j]
//                                                 [n = nt*16 + (lane&15)]
// Lbt layout: ((rt*256 + ktile)*512) + lane*8 + j holds
//             L[m = rt*16+(lane&15)][k = ktile*32 + 8*(lane>>4) + j]

// ---- head: y_acc = x @ W0 ; zbt0 = frag(bf16(x)) ---------------------------
__global__ __launch_bounds__(256) void head_kernel(
    const float* __restrict__ x, const float* __restrict__ W0,
    float* __restrict__ y_out, u16* __restrict__ zbt0) {
  __shared__ float Ws[1024];
  __shared__ u16 zsb[256][34];
  const int t = threadIdx.x;
  for (int i = t; i < 1024; i += 256) Ws[i] = W0[i];
  const int m = blockIdx.x * 256 + t;
  float z[32];
  const float4* xr = (const float4*)(x + (size_t)m * 32);
#pragma unroll
  for (int i = 0; i < 8; i++) {
    float4 v = xr[i];
    z[4 * i] = v.x; z[4 * i + 1] = v.y; z[4 * i + 2] = v.z; z[4 * i + 3] = v.w;
  }
#pragma unroll
  for (int c = 0; c < 32; c++) zsb[t][c] = f2bf(z[c]);
  __syncthreads();
  float acc[32];
#pragma unroll
  for (int j = 0; j < 32; j++) acc[j] = 0.f;
#pragma unroll
  for (int c = 0; c < 32; c++) {
#pragma unroll
    for (int j = 0; j < 32; j++) acc[j] += z[c] * Ws[c * 32 + j];
  }
  float4* yo = (float4*)(y_out + (size_t)m * 32);
#pragma unroll
  for (int i = 0; i < 8; i++) {
    float4 v; v.x = acc[4 * i]; v.y = acc[4 * i + 1];
    v.z = acc[4 * i + 2]; v.w = acc[4 * i + 3];
    yo[i] = v;
  }
  const int lane = t & 63, w = t >> 6;
  const int l15 = lane & 15, l4 = lane >> 4;
#pragma unroll
  for (int i = 0; i < 4; i++) {
    int tile = w * 4 + i;
    int ktl = tile >> 1, nt = tile & 1;
    Frag fr;
#pragma unroll
    for (int j = 0; j < 8; j++) fr.s[j] = zsb[ktl * 32 + 8 * l4 + j][nt * 16 + l15];
    size_t kt_g = (size_t)blockIdx.x * 8 + ktl;
    *(u32x4*)(zbt0 + ((kt_g * 2 + nt) * 64 + lane) * 8) = fr.q;
  }
}

// ---- conv: pure stream transform L (f32, NT) -> Lbt (bf16 frag-tiled) ------
// Thread owns 4 rows x 8 cols. Loads: 2 x f32x4 per row (wave: 2KB/row
// contiguous). Stores: 4 x 16B = one full 64B sector of Lbt. No LDS/sync.
__global__ __launch_bounds__(256) void conv_kernel(
    const float* __restrict__ L, u16* __restrict__ Lbt) {
  const int gid = blockIdx.x * 256 + threadIdx.x;  // 0 .. 2M-1
  const int cg = gid & 1023;        // col group: c = cg*8
  const int rg = gid >> 10;         // row group: r = rg*4
  const int c = cg * 8;
  const int r = rg * 4;
  const int rt = r >> 4;
  const int ktile = c >> 5;
  const int q = (c & 31) >> 3;      // 0..3
  const float* src = L + (size_t)r * M_DIM + c;
  u16* dst = Lbt + ((size_t)rt * 256 + ktile) * 512 + ((r & 15) + 16 * q) * 8;

  f32x4 v[4][2];
#pragma unroll
  for (int i = 0; i < 4; i++) {
    const float* sr = src + (size_t)i * M_DIM;
    v[i][0] = __builtin_nontemporal_load((const f32x4*)sr);
    v[i][1] = __builtin_nontemporal_load((const f32x4*)(sr + 4));
  }
#pragma unroll
  for (int i = 0; i < 4; i++) {
    Frag fr;
#pragma unroll
    for (int h = 0; h < 2; h++) {
      fr.s[4 * h + 0] = f2bf(v[i][h][0]);
      fr.s[4 * h + 1] = f2bf(v[i][h][1]);
      fr.s[4 * h + 2] = f2bf(v[i][h][2]);
      fr.s[4 * h + 3] = f2bf(v[i][h][3]);
    }
    *(u32x4*)(dst + i * 8) = fr.q;
  }
}

// ---- fpass: z_next = L @ z (full-K, 8-wave K-split) + y += z_next @ Wk -----
template <bool LAST>
__global__ __launch_bounds__(512, 4) void fpass_kernel(
    const u16* __restrict__ Lbt, const u16* __restrict__ zbt,
    const float* __restrict__ Wk, const float* __restrict__ y_in,
    float* __restrict__ y_out, u16* __restrict__ zbt_out) {
  __shared__ float red[8][16][33];
  __shared__ float Ws[1024];
  __shared__ float zs[16][33];
  __shared__ u16 zsb[16][36];
  const int t = threadIdx.x;
  const int lane = t & 63, w = t >> 6;
  const int l15 = lane & 15, l4 = lane >> 4;
  const int bx = blockIdx.x;  // [0,512) row tile
  for (int i = t; i < 1024; i += 512) Ws[i] = Wk[i];

  const u16* ap = Lbt + ((size_t)bx * 256 + w * 32) * 512 + lane * 8;
  const u16* bp = zbt + (size_t)(w * 32) * 1024 + lane * 8;

  f32x4 acc0 = {0.f, 0.f, 0.f, 0.f};
  f32x4 acc1 = {0.f, 0.f, 0.f, 0.f};
#pragma unroll 8
  for (int kt = 0; kt < 32; kt++) {
    Frag fa, fb0, fb1;
    fa.q = *(const u32x4*)(ap + (size_t)kt * 512);
    fb0.q = *(const u32x4*)(bp + (size_t)kt * 1024);
    fb1.q = *(const u32x4*)(bp + (size_t)kt * 1024 + 512);
    acc0 = __builtin_amdgcn_mfma_f32_16x16x32_bf16(fa.f, fb0.f, acc0, 0, 0, 0);
    acc1 = __builtin_amdgcn_mfma_f32_16x16x32_bf16(fa.f, fb1.f, acc1, 0, 0, 0);
  }
#pragma unroll
  for (int r = 0; r < 4; r++) {
    red[w][4 * l4 + r][l15] = acc0[r];
    red[w][4 * l4 + r][l15 + 16] = acc1[r];
  }
  __syncthreads();
  const int row = t >> 5, j = t & 31;
  float v = 0.f;
#pragma unroll
  for (int s = 0; s < 8; s++) v += red[s][row][j];
  zs[row][j] = v;
  zsb[row][j] = f2bf(v);
  __syncthreads();
  float yv = y_in[(size_t)(bx * 16 + row) * 32 + j];
#pragma unroll
  for (int c = 0; c < 32; c++) yv += zs[row][c] * Ws[c * 32 + j];
  y_out[(size_t)(bx * 16 + row) * 32 + j] = yv;

  if (!LAST && t < 64) {
    const int nt = t >> 5, li = t & 31;
    const int kt = bx >> 1, h = bx & 1;
    Frag fr;
#pragma unroll
    for (int jj = 0; jj < 8; jj++)
      fr.s[jj] = zsb[8 * (li >> 4) + jj][nt * 16 + (li & 15)];
    *(u32x4*)(zbt_out + (size_t)((kt * 2 + nt) * 64 + 32 * h + li) * 8) = fr.q;
  }
}

extern "C" void kernel_launch(void* const* d_in, const int* in_sizes, int n_in,
                              void* d_out, int out_size, void* d_ws,
                              size_t ws_size, hipStream_t stream) {
  const float* x = (const float*)d_in[0];
  const float* L = (const float*)d_in[1];
  const float* W = (const float*)d_in[2];
  float* y = (float*)d_out;
  char* ws = (char*)d_ws;

  const size_t ZT = (size_t)512 << 10;  // 512 KB per zbt
  u16* zbt0 = (u16*)(ws + 0 * ZT);
  u16* zbt1 = (u16*)(ws + 1 * ZT);
  u16* zbt2 = (u16*)(ws + 2 * ZT);
  u16* zbt3 = (u16*)(ws + 3 * ZT);
  float* y_acc = (float*)(ws + ((size_t)10 << 20));   // 1 MB @ 10 MiB
  u16* Lbt = (u16*)(ws + ((size_t)12 << 20));         // 128 MiB @ 12 MiB

  head_kernel<<<32, 256, 0, stream>>>(x, W, y_acc, zbt0);
  conv_kernel<<<8192, 256, 0, stream>>>(L, Lbt);
  fpass_kernel<false><<<512, 512, 0, stream>>>(Lbt, zbt0, W + 1024, y_acc, y_acc, zbt1);
  fpass_kernel<false><<<512, 512, 0, stream>>>(Lbt, zbt1, W + 2048, y_acc, y_acc, zbt2);
  fpass_kernel<false><<<512, 512, 0, stream>>>(Lbt, zbt2, W + 3072, y_acc, y_acc, zbt3);
  fpass_kernel<true><<<512, 512, 0, stream>>>(Lbt, zbt3, W + 4096, y_acc, y, (u16*)0);
}

// Round 8
// 174.585 us; speedup vs baseline: 1.3004x; 1.3004x over previous
//
#include <hip/hip_runtime.h>

typedef unsigned short u16;
typedef unsigned int u32;
typedef __bf16 bf16x8 __attribute__((ext_vector_type(8)));
typedef float f32x4 __attribute__((ext_vector_type(4)));
typedef u32 u32x2 __attribute__((ext_vector_type(2)));
typedef u32 u32x4 __attribute__((ext_vector_type(4)));

#define M_DIM 8192
#define CCH 512              /* conv staging chunk (k-cols) */
#define NCH (M_DIM / CCH)    /* 16 chunks */

__device__ __forceinline__ u16 f2bf(float f) {
  return __builtin_bit_cast(u16, (__bf16)f);  // HW RNE cvt
}

union Frag {
  bf16x8 f;
  u16 s[8];
  u32x2 h2[2];
  u32x4 q;
};

// zbt layout: ((kt*2 + nt)*64 + lane)*8 + j holds z[k = kt*32 + 8*(lane>>4)+j]
//                                                 [n = nt*16 + (lane&15)]
// Lbt layout: ((rt*256 + ktile)*512) + lane*8 + j holds
//             L[m = rt*16+(lane&15)][k = ktile*32 + 8*(lane>>4) + j]

// ---- head: y_acc = x @ W0 ; zbt0 = frag(bf16(x)) ---------------------------
__global__ __launch_bounds__(256) void head_kernel(
    const float* __restrict__ x, const float* __restrict__ W0,
    float* __restrict__ y_out, u16* __restrict__ zbt0) {
  __shared__ float Ws[1024];
  __shared__ u16 zsb[256][34];
  const int t = threadIdx.x;
  for (int i = t; i < 1024; i += 256) Ws[i] = W0[i];
  const int m = blockIdx.x * 256 + t;
  float z[32];
  const float4* xr = (const float4*)(x + (size_t)m * 32);
#pragma unroll
  for (int i = 0; i < 8; i++) {
    float4 v = xr[i];
    z[4 * i] = v.x; z[4 * i + 1] = v.y; z[4 * i + 2] = v.z; z[4 * i + 3] = v.w;
  }
#pragma unroll
  for (int c = 0; c < 32; c++) zsb[t][c] = f2bf(z[c]);
  __syncthreads();
  float acc[32];
#pragma unroll
  for (int j = 0; j < 32; j++) acc[j] = 0.f;
#pragma unroll
  for (int c = 0; c < 32; c++) {
#pragma unroll
    for (int j = 0; j < 32; j++) acc[j] += z[c] * Ws[c * 32 + j];
  }
  float4* yo = (float4*)(y_out + (size_t)m * 32);
#pragma unroll
  for (int i = 0; i < 8; i++) {
    float4 v; v.x = acc[4 * i]; v.y = acc[4 * i + 1];
    v.z = acc[4 * i + 2]; v.w = acc[4 * i + 3];
    yo[i] = v;
  }
  const int lane = t & 63, w = t >> 6;
  const int l15 = lane & 15, l4 = lane >> 4;
#pragma unroll
  for (int i = 0; i < 4; i++) {
    int tile = w * 4 + i;
    int ktl = tile >> 1, nt = tile & 1;
    Frag fr;
#pragma unroll
    for (int j = 0; j < 8; j++) fr.s[j] = zsb[ktl * 32 + 8 * l4 + j][nt * 16 + l15];
    size_t kt_g = (size_t)blockIdx.x * 8 + ktl;
    *(u32x4*)(zbt0 + ((kt_g * 2 + nt) * 64 + lane) * 8) = fr.q;
  }
}

// ---- conv (round-5 proven form): L -> Lbt + z1 = L@z0 + y+=z1@W1 + zbt1 ----
__global__ __launch_bounds__(512, 4) void conv_kernel(
    const float* __restrict__ L, const u16* __restrict__ zbt0,
    const float* __restrict__ W1, const float* __restrict__ y_in,
    float* __restrict__ y_out, u16* __restrict__ Lbt,
    u16* __restrict__ zbt_out) {
  __shared__ u16 At[2][16][520];
  __shared__ float red[8][16][33];
  __shared__ float Ws[1024];
  __shared__ float zs[16][33];
  __shared__ u16 zsb[16][36];
  const int t = threadIdx.x;
  const int lane = t & 63, w = t >> 6;
  const int l15 = lane & 15, l4 = lane >> 4;
  const int bx = blockIdx.x;  // [0,512) row tile
  const int r0 = bx * 16;
  for (int i = t; i < 1024; i += 512) Ws[i] = W1[i];

  const int srow = t >> 5, scg = t & 31;
  const float* sbase = L + (size_t)(r0 + srow) * M_DIM + scg * 4;

  auto stage = [&](int c, int buf) {
    const float* src = sbase + c * CCH;
    u16* dst = &At[buf][srow][scg * 4];
#pragma unroll
    for (int seg = 0; seg < 4; seg++) {
      f32x4 v = __builtin_nontemporal_load((const f32x4*)(src + seg * 128));
      u32x2 p;
      p[0] = (u32)f2bf(v[0]) | ((u32)f2bf(v[1]) << 16);
      p[1] = (u32)f2bf(v[2]) | ((u32)f2bf(v[3]) << 16);
      *(u32x2*)(dst + seg * 128) = p;
    }
  };

  f32x4 acc0 = {0.f, 0.f, 0.f, 0.f};
  f32x4 acc1 = {0.f, 0.f, 0.f, 0.f};

  stage(0, 0);
  int buf = 0;
  for (int c = 0; c < NCH; c++) {
    __syncthreads();
    if (c + 1 < NCH) stage(c + 1, buf ^ 1);
#pragma unroll
    for (int i = 0; i < 2; i++) {
      const int ktl = c * 16 + w * 2 + i;  // global k-tile [0,256)
      Frag fa;
      fa.q = *(const u32x4*)&At[buf][l15][(w * 2 + i) * 32 + 8 * l4];
      *(u32x4*)(Lbt + ((size_t)bx * 256 + ktl) * 512 + lane * 8) = fa.q;
      Frag fb0, fb1;
      size_t bo = ((size_t)ktl * 2) * 512 + lane * 8;
      fb0.q = *(const u32x4*)(zbt0 + bo);
      fb1.q = *(const u32x4*)(zbt0 + bo + 512);
      acc0 = __builtin_amdgcn_mfma_f32_16x16x32_bf16(fa.f, fb0.f, acc0, 0, 0, 0);
      acc1 = __builtin_amdgcn_mfma_f32_16x16x32_bf16(fa.f, fb1.f, acc1, 0, 0, 0);
    }
    buf ^= 1;
  }

#pragma unroll
  for (int r = 0; r < 4; r++) {
    red[w][4 * l4 + r][l15] = acc0[r];
    red[w][4 * l4 + r][l15 + 16] = acc1[r];
  }
  __syncthreads();
  const int row = t >> 5, j = t & 31;
  float v = 0.f;
#pragma unroll
  for (int s = 0; s < 8; s++) v += red[s][row][j];
  zs[row][j] = v;
  zsb[row][j] = f2bf(v);
  __syncthreads();
  float yv = y_in[(size_t)(r0 + row) * 32 + j];
#pragma unroll
  for (int c = 0; c < 32; c++) yv += zs[row][c] * Ws[c * 32 + j];
  y_out[(size_t)(r0 + row) * 32 + j] = yv;

  if (t < 64) {
    const int nt = t >> 5, li = t & 31;
    const int kt = bx >> 1, h = bx & 1;
    Frag fr;
#pragma unroll
    for (int jj = 0; jj < 8; jj++)
      fr.s[jj] = zsb[8 * (li >> 4) + jj][nt * 16 + (li & 15)];
    *(u32x4*)(zbt_out + (size_t)((kt * 2 + nt) * 64 + 32 * h + li) * 8) = fr.q;
  }
}

// ---- fpass: z_next = L @ z via per-wave global_load_lds pipeline -----------
// Wave w owns k-tiles [w*32, w*32+32): streams its 32 KB Lbt slice through a
// private 2x2KB LDS dbuf (no barriers in K loop), counted vmcnt keeps the
// next chunk in flight under the MFMAs. Then 8-way reduce + y+=z@Wk + emit.
template <bool LAST>
__global__ __launch_bounds__(512, 4) void fpass_kernel(
    const u16* __restrict__ Lbt, const u16* __restrict__ zbt,
    const float* __restrict__ Wk, const float* __restrict__ y_in,
    float* __restrict__ y_out, u16* __restrict__ zbt_out) {
  __shared__ u16 At[8][2][1024];   // 32 KB: per-wave double buffer
  __shared__ float red[8][16][33];
  __shared__ float Ws[1024];
  __shared__ float zs[16][33];
  __shared__ u16 zsb[16][36];
  const int t = threadIdx.x;
  const int lane = t & 63, w = t >> 6;
  const int l15 = lane & 15, l4 = lane >> 4;
  const int bx = blockIdx.x;  // [0,512) row tile
  for (int i = t; i < 1024; i += 512) Ws[i] = Wk[i];

  const u16* asrc = Lbt + ((size_t)bx * 256 + w * 32) * 512;  // 32 KB slice
  const u16* bp = zbt + (size_t)(w * 32) * 1024 + lane * 8;

  auto issue = [&](int c) {
    const int b = c & 1;
    const u16* s = asrc + (size_t)c * 1024 + lane * 8;
    __builtin_amdgcn_global_load_lds(
        (const __attribute__((address_space(1))) u32*)s,
        (__attribute__((address_space(3))) u32*)&At[w][b][lane * 8], 16, 0, 0);
    __builtin_amdgcn_global_load_lds(
        (const __attribute__((address_space(1))) u32*)(s + 512),
        (__attribute__((address_space(3))) u32*)&At[w][b][512 + lane * 8], 16, 0, 0);
  };

  f32x4 acc0 = {0.f, 0.f, 0.f, 0.f};
  f32x4 acc1 = {0.f, 0.f, 0.f, 0.f};

  issue(0);
  for (int c = 0; c < 16; c++) {
    if (c + 1 < 16) {
      issue(c + 1);
      asm volatile("s_waitcnt vmcnt(2)" ::: "memory");  // wait chunk c only
    } else {
      asm volatile("s_waitcnt vmcnt(0)" ::: "memory");
    }
    __builtin_amdgcn_sched_barrier(0);
#pragma unroll
    for (int i = 0; i < 2; i++) {
      Frag fa, fb0, fb1;
      fa.q = *(const u32x4*)&At[w][c & 1][i * 512 + lane * 8];
      size_t bo = (size_t)(c * 2 + i) * 1024;
      fb0.q = *(const u32x4*)(bp + bo);
      fb1.q = *(const u32x4*)(bp + bo + 512);
      acc0 = __builtin_amdgcn_mfma_f32_16x16x32_bf16(fa.f, fb0.f, acc0, 0, 0, 0);
      acc1 = __builtin_amdgcn_mfma_f32_16x16x32_bf16(fa.f, fb1.f, acc1, 0, 0, 0);
    }
  }

#pragma unroll
  for (int r = 0; r < 4; r++) {
    red[w][4 * l4 + r][l15] = acc0[r];
    red[w][4 * l4 + r][l15 + 16] = acc1[r];
  }
  __syncthreads();
  const int row = t >> 5, j = t & 31;
  float v = 0.f;
#pragma unroll
  for (int s = 0; s < 8; s++) v += red[s][row][j];
  zs[row][j] = v;
  zsb[row][j] = f2bf(v);
  __syncthreads();
  float yv = y_in[(size_t)(bx * 16 + row) * 32 + j];
#pragma unroll
  for (int c = 0; c < 32; c++) yv += zs[row][c] * Ws[c * 32 + j];
  y_out[(size_t)(bx * 16 + row) * 32 + j] = yv;

  if (!LAST && t < 64) {
    const int nt = t >> 5, li = t & 31;
    const int kt = bx >> 1, h = bx & 1;
    Frag fr;
#pragma unroll
    for (int jj = 0; jj < 8; jj++)
      fr.s[jj] = zsb[8 * (li >> 4) + jj][nt * 16 + (li & 15)];
    *(u32x4*)(zbt_out + (size_t)((kt * 2 + nt) * 64 + 32 * h + li) * 8) = fr.q;
  }
}

extern "C" void kernel_launch(void* const* d_in, const int* in_sizes, int n_in,
                              void* d_out, int out_size, void* d_ws,
                              size_t ws_size, hipStream_t stream) {
  const float* x = (const float*)d_in[0];
  const float* L = (const float*)d_in[1];
  const float* W = (const float*)d_in[2];
  float* y = (float*)d_out;
  char* ws = (char*)d_ws;

  const size_t ZT = (size_t)512 << 10;  // 512 KB per zbt
  u16* zbt0 = (u16*)(ws + 0 * ZT);
  u16* zbt1 = (u16*)(ws + 1 * ZT);
  u16* zbt2 = (u16*)(ws + 2 * ZT);
  u16* zbt3 = (u16*)(ws + 3 * ZT);
  float* y_acc = (float*)(ws + ((size_t)10 << 20));   // 1 MB @ 10 MiB
  u16* Lbt = (u16*)(ws + ((size_t)12 << 20));         // 128 MiB @ 12 MiB

  head_kernel<<<32, 256, 0, stream>>>(x, W, y_acc, zbt0);
  conv_kernel<<<512, 512, 0, stream>>>(L, zbt0, W + 1024, y_acc, y_acc, Lbt, zbt1);
  fpass_kernel<false><<<512, 512, 0, stream>>>(Lbt, zbt1, W + 2048, y_acc, y_acc, zbt2);
  fpass_kernel<false><<<512, 512, 0, stream>>>(Lbt, zbt2, W + 3072, y_acc, y_acc, zbt3);
  fpass_kernel<true><<<512, 512, 0, stream>>>(Lbt, zbt3, W + 4096, y_acc, y, (u16*)0);
}